// Round 4
// baseline (172.502 us; speedup 1.0000x reference)
//
#include <hip/hip_runtime.h>

#define NB 2
#define NH 8
#define NS 2048
#define ND 64
#define QBLK 32
#define KBLK 32
#define NHALF 1024            // keys per half (k-split factor 2)
#define NT (NHALF / KBLK)     // 32 tiles per half
#define LDST 72               // Q/K/P row stride in f16 (144B)
#define VST  40               // VT row stride in f16 (80B) -> conflict-friendly, no swizzle

typedef _Float16 f16x4 __attribute__((ext_vector_type(4)));
typedef _Float16 f16x8 __attribute__((ext_vector_type(8)));
typedef float    f32x4 __attribute__((ext_vector_type(4)));

#define MFMA16(A,B,C) __builtin_amdgcn_mfma_f32_16x16x32_f16((A),(B),(C),0,0,0)

// ---------------- pass A: per-half softmax stats (m, l) ----------------
__global__ __launch_bounds__(128)
void sdpa_stats(const float* __restrict__ Qg, const float* __restrict__ Kg,
                float2* __restrict__ MLg)
{
    const int tid = threadIdx.x;
    const int w = tid >> 6, lane = tid & 63, lg = lane >> 4, lc = lane & 15;
    const int bh = blockIdx.x, qt = blockIdx.y, half = blockIdx.z;

    const size_t base = (size_t)bh * NS * ND;
    const float* Qp = Qg + base + (size_t)qt * QBLK * ND;
    const float* Kp = Kg + base + (size_t)half * NHALF * ND;

    __shared__ __align__(16) _Float16 Qs[QBLK * LDST];
    __shared__ __align__(16) _Float16 Ks[KBLK * LDST];

    const int srow = tid >> 4;          // 0..7
    const int sd0  = (tid & 15) * 4;    // 0..60

    #pragma unroll
    for (int it = 0; it < 4; ++it) {    // Q scaled by 1/T = 1/8 (exact)
        const int r = srow + 8 * it;
        float4 f = *(const float4*)&Qp[(size_t)r * ND + sd0];
        f16x4 h = { (_Float16)(f.x*0.125f), (_Float16)(f.y*0.125f),
                    (_Float16)(f.z*0.125f), (_Float16)(f.w*0.125f) };
        *(f16x4*)&Qs[r * LDST + sd0] = h;
    }
    __syncthreads();

    const int q = 16 * w + lc;
    const f16x8 qf0 = *(const f16x8*)&Qs[q * LDST + 8 * lg];
    const f16x8 qf1 = *(const f16x8*)&Qs[q * LDST + 8 * lg + 32];

    float m = -3.0e38f, l = 0.f;
    float4 ka[4];

    auto loadK = [&](int t) {
        #pragma unroll
        for (int it = 0; it < 4; ++it)
            ka[it] = *(const float4*)&Kp[(size_t)(t * KBLK + srow + 8 * it) * ND + sd0];
    };
    auto writeK = [&]() {
        #pragma unroll
        for (int it = 0; it < 4; ++it) {
            f16x4 h = { (_Float16)ka[it].x, (_Float16)ka[it].y,
                        (_Float16)ka[it].z, (_Float16)ka[it].w };
            *(f16x4*)&Ks[(srow + 8 * it) * LDST + sd0] = h;
        }
    };

    loadK(0);
    for (int t = 0; t < NT; ++t) {
        __syncthreads();
        writeK();
        __syncthreads();
        loadK(t + 1 < NT ? t + 1 : 0);

        f32x4 s0 = {0,0,0,0}, s1 = {0,0,0,0};
        {
            f16x8 a0 = *(const f16x8*)&Ks[lc * LDST + 8 * lg];
            f16x8 a1 = *(const f16x8*)&Ks[lc * LDST + 8 * lg + 32];
            s0 = MFMA16(a0, qf0, s0); s0 = MFMA16(a1, qf1, s0);
            f16x8 b0 = *(const f16x8*)&Ks[(16 + lc) * LDST + 8 * lg];
            f16x8 b1 = *(const f16x8*)&Ks[(16 + lc) * LDST + 8 * lg + 32];
            s1 = MFMA16(b0, qf0, s1); s1 = MFMA16(b1, qf1, s1);
        }
        float tmax = -3.0e38f;
        #pragma unroll
        for (int r = 0; r < 4; ++r) tmax = fmaxf(tmax, fmaxf(s0[r], s1[r]));
        tmax = fmaxf(tmax, __shfl_xor(tmax, 16));
        tmax = fmaxf(tmax, __shfl_xor(tmax, 32));
        const float mn = fmaxf(m, tmax);
        float ts = 0.f;
        #pragma unroll
        for (int r = 0; r < 4; ++r)
            ts += __expf(s0[r] - mn) + __expf(s1[r] - mn);
        ts += __shfl_xor(ts, 16);
        ts += __shfl_xor(ts, 32);
        l = l * __expf(m - mn) + ts;
        m = mn;
    }
    if (lg == 0)
        MLg[((size_t)half * NB * NH + bh) * NS + qt * QBLK + q] = make_float2(m, l);
}

// ---------------- pass B: attn write + PV partial ----------------
__global__ __launch_bounds__(128)
void sdpa_passb(const float* __restrict__ Qg, const float* __restrict__ Kg,
                const float* __restrict__ Vg, const float2* __restrict__ MLg,
                float* __restrict__ Ag,
                float* __restrict__ dst0, float* __restrict__ dst1,
                int mode0, int mode1, int halfBase)
{
    const int tid = threadIdx.x;
    const int w = tid >> 6, lane = tid & 63, lg = lane >> 4, lc = lane & 15;
    const int bh = blockIdx.x, qt = blockIdx.y;
    const int half = halfBase + blockIdx.z;
    float* Odst = blockIdx.z ? dst1 : dst0;
    const int mode = blockIdx.z ? mode1 : mode0;

    const size_t base = (size_t)bh * NS * ND;
    const float* Qp = Qg + base + (size_t)qt * QBLK * ND;
    const float* Kp = Kg + base + (size_t)half * NHALF * ND;
    const float* Vp = Vg + base + (size_t)half * NHALF * ND;
    float*       Op = Odst + base + (size_t)qt * QBLK * ND;
    float*       Ap = Ag + (size_t)bh * NS * NS + (size_t)qt * QBLK * NS
                       + (size_t)half * NHALF;

    __shared__ __align__(16) _Float16 Qs[QBLK * LDST];
    __shared__ __align__(16) _Float16 Ks[KBLK * LDST];
    __shared__ __align__(16) _Float16 Ps[QBLK * LDST];
    __shared__ __align__(16) _Float16 VT[ND * VST];

    const int srow = tid >> 4;          // 0..7
    const int sd0  = (tid & 15) * 4;
    const int kb   = tid & 7;           // V 4-key block
    const int db   = tid >> 3;          // 0..15, V 4-d block

    #pragma unroll
    for (int it = 0; it < 4; ++it) {
        const int r = srow + 8 * it;
        float4 f = *(const float4*)&Qp[(size_t)r * ND + sd0];
        f16x4 h = { (_Float16)(f.x*0.125f), (_Float16)(f.y*0.125f),
                    (_Float16)(f.z*0.125f), (_Float16)(f.w*0.125f) };
        *(f16x4*)&Qs[r * LDST + sd0] = h;
    }
    __syncthreads();

    const int q = 16 * w + lc;
    const f16x8 qf0 = *(const f16x8*)&Qs[q * LDST + 8 * lg];
    const f16x8 qf1 = *(const f16x8*)&Qs[q * LDST + 8 * lg + 32];

    // merged softmax stats for this lane's q-row
    float m, il;
    {
        const size_t qi = (size_t)qt * QBLK + q;
        const float2 s0 = MLg[(size_t)bh * NS + qi];
        const float2 s1 = MLg[((size_t)NB * NH + bh) * NS + qi];
        m = fmaxf(s0.x, s1.x);
        const float l = s0.y * __expf(s0.x - m) + s1.y * __expf(s1.x - m);
        il = 1.0f / l;
    }

    float4 ka[4], vr[4];
    auto loadK = [&](int t) {
        #pragma unroll
        for (int it = 0; it < 4; ++it)
            ka[it] = *(const float4*)&Kp[(size_t)(t * KBLK + srow + 8 * it) * ND + sd0];
    };
    auto writeK = [&]() {
        #pragma unroll
        for (int it = 0; it < 4; ++it) {
            f16x4 h = { (_Float16)ka[it].x, (_Float16)ka[it].y,
                        (_Float16)ka[it].z, (_Float16)ka[it].w };
            *(f16x4*)&Ks[(srow + 8 * it) * LDST + sd0] = h;
        }
    };
    auto loadV = [&](int t) {            // 4 keys x 4 d per thread, coalesced rows
        #pragma unroll
        for (int r = 0; r < 4; ++r)
            vr[r] = *(const float4*)&Vp[(size_t)(t * KBLK + 4 * kb + r) * ND + 4 * db];
    };
    auto writeVT = [&]() {               // in-register 4x4 transpose -> b64 writes
        const float* p0 = (const float*)&vr[0];
        const float* p1 = (const float*)&vr[1];
        const float* p2 = (const float*)&vr[2];
        const float* p3 = (const float*)&vr[3];
        #pragma unroll
        for (int j = 0; j < 4; ++j) {
            f16x4 col = { (_Float16)p0[j], (_Float16)p1[j],
                          (_Float16)p2[j], (_Float16)p3[j] };
            *(f16x4*)&VT[(4 * db + j) * VST + 4 * kb] = col;
        }
    };

    f32x4 acc[4];
    #pragma unroll
    for (int dt = 0; dt < 4; ++dt) acc[dt] = {0,0,0,0};

    loadK(0); loadV(0);
    for (int t = 0; t < NT; ++t) {
        __syncthreads();
        writeK(); writeVT();
        __syncthreads();
        const int nt = t + 1 < NT ? t + 1 : 0;
        loadK(nt); loadV(nt);

        // S^T tile (rows = keys, cols = q)
        f32x4 s0 = {0,0,0,0}, s1 = {0,0,0,0};
        {
            f16x8 a0 = *(const f16x8*)&Ks[lc * LDST + 8 * lg];
            f16x8 a1 = *(const f16x8*)&Ks[lc * LDST + 8 * lg + 32];
            s0 = MFMA16(a0, qf0, s0); s0 = MFMA16(a1, qf1, s0);
            f16x8 b0 = *(const f16x8*)&Ks[(16 + lc) * LDST + 8 * lg];
            f16x8 b1 = *(const f16x8*)&Ks[(16 + lc) * LDST + 8 * lg + 32];
            s1 = MFMA16(b0, qf0, s1); s1 = MFMA16(b1, qf1, s1);
        }
        // p = exp(s - m) * il : attn store (fp32) + P stash (f16)
        f32x4 p0, p1;
        #pragma unroll
        for (int r = 0; r < 4; ++r) {
            p0[r] = __expf(s0[r] - m) * il;
            p1[r] = __expf(s1[r] - m) * il;
        }
        *(f32x4*)&Ap[(size_t)q * NS + t * KBLK + 4 * lg]      = p0;
        *(f32x4*)&Ap[(size_t)q * NS + t * KBLK + 16 + 4 * lg] = p1;
        f16x4 h0 = { (_Float16)p0[0], (_Float16)p0[1], (_Float16)p0[2], (_Float16)p0[3] };
        f16x4 h1 = { (_Float16)p1[0], (_Float16)p1[1], (_Float16)p1[2], (_Float16)p1[3] };
        *(f16x4*)&Ps[q * LDST + 4 * lg]      = h0;
        *(f16x4*)&Ps[q * LDST + 16 + 4 * lg] = h1;
        asm volatile("s_waitcnt lgkmcnt(0)" ::: "memory");  // wave-private P rows

        // PV: O^T += V^T . P^T  (K-dim = 32 keys, one MFMA per d-subtile)
        const f16x8 bf = *(const f16x8*)&Ps[q * LDST + 8 * lg];
        #pragma unroll
        for (int dt = 0; dt < 4; ++dt) {
            f16x8 af = *(const f16x8*)&VT[(16 * dt + lc) * VST + 8 * lg];
            acc[dt] = MFMA16(af, bf, acc[dt]);
        }
    }

    // O^T[d = 16dt+4lg+r][q] -> Op[q][d], partial per half
    #pragma unroll
    for (int dt = 0; dt < 4; ++dt) {
        f32x4 o = acc[dt];
        float* addr = &Op[(size_t)q * ND + 16 * dt + 4 * lg];
        if (mode) o = o + *(const f32x4*)addr;
        *(f32x4*)addr = o;
    }
}

// ---------------- O merge: Og += wsO ----------------
__global__ __launch_bounds__(256)
void add_o(float* __restrict__ O, const float* __restrict__ P)
{
    const size_t i = (size_t)blockIdx.x * 256 + threadIdx.x;
    f32x4* O4 = (f32x4*)O;
    const f32x4* P4 = (const f32x4*)P;
    O4[i] = O4[i] + P4[i];
}

extern "C" void kernel_launch(void* const* d_in, const int* in_sizes, int n_in,
                              void* d_out, int out_size, void* d_ws, size_t ws_size,
                              hipStream_t stream) {
    const float* q = (const float*)d_in[0];
    const float* k = (const float*)d_in[1];
    const float* v = (const float*)d_in[2];
    float* out  = (float*)d_out;
    float* attn = out + (size_t)NB * NH * NS * ND;   // outputs: (output, attn)

    float2* ml  = (float2*)d_ws;                      // [2][B*H][S] = 512 KB
    const size_t mlBytes = (size_t)2 * NB * NH * NS * sizeof(float2);
    float* wsO  = (float*)((char*)d_ws + mlBytes);    // [B*H][S][D] = 8 MB
    const size_t oElems = (size_t)NB * NH * NS * ND;
    const size_t need = mlBytes + oElems * sizeof(float);

    dim3 grid2(NB * NH, NS / QBLK, 2);   // x = bh (XCD affinity), y = q-tile, z = half
    sdpa_stats<<<grid2, 128, 0, stream>>>(q, k, ml);

    if (ws_size >= need) {
        // half0 -> out(O region) store; half1 -> ws store; then add
        sdpa_passb<<<grid2, 128, 0, stream>>>(q, k, v, ml, attn,
                                              out, wsO, 0, 0, 0);
        add_o<<<oElems / (256 * 4), 256, 0, stream>>>(out, wsO);
    } else {
        dim3 grid1(NB * NH, NS / QBLK, 1);
        sdpa_passb<<<grid1, 128, 0, stream>>>(q, k, v, ml, attn,
                                              out, out, 0, 0, 0);   // half0 store
        sdpa_passb<<<grid1, 128, 0, stream>>>(q, k, v, ml, attn,
                                              out, out, 1, 1, 1);   // half1 add
    }
}

// Round 5
// 118.522 us; speedup vs baseline: 1.4554x; 1.4554x over previous
//
#include <hip/hip_runtime.h>

#define NB 2
#define NH 8
#define NS 2048
#define ND 64
#define QBLK 64
#define KBLK 128
#define NKT (NS / KBLK)   // 16
#define QST 76            // Q/K LDS row stride (f16): 152B, 8B-aligned, 16-bank-start spread
#define KST 76
#define VST 140           // VT row stride: 280B
#define PST 132           // P row stride: 264B

typedef _Float16 f16x4 __attribute__((ext_vector_type(4)));
typedef _Float16 f16x8 __attribute__((ext_vector_type(8)));
typedef float    f32x4 __attribute__((ext_vector_type(4)));

#define MFMA16(A,B,C) __builtin_amdgcn_mfma_f32_16x16x32_f16((A),(B),(C),0,0,0)

static __device__ __forceinline__ f16x8 cat8(f16x4 a, f16x4 b) {
    return __builtin_shufflevector(a, b, 0, 1, 2, 3, 4, 5, 6, 7);
}
static __device__ __forceinline__ f16x8 lds8(const _Float16* p) {
    f16x4 a = *(const f16x4*)p;          // 8B-aligned ds_read_b64
    f16x4 b = *(const f16x4*)(p + 4);
    return cat8(a, b);
}

__global__ __launch_bounds__(256)
void sdpa_kernel(const float* __restrict__ Qg, const float* __restrict__ Kg,
                 const float* __restrict__ Vg, float* __restrict__ Og,
                 float* __restrict__ Ag)
{
    const int tid  = threadIdx.x;
    const int w    = tid >> 6;
    const int lane = tid & 63;
    const int lg   = lane >> 4;
    const int lc   = lane & 15;
    const int qt   = blockIdx.x;
    const int bh   = blockIdx.y;

    const size_t base = (size_t)bh * NS * ND;
    const float* Qp = Qg + base + (size_t)qt * QBLK * ND;
    const float* Kp = Kg + base;
    const float* Vp = Vg + base;
    float*       Op = Og + base + (size_t)qt * QBLK * ND;
    float*       Ap = Ag + (size_t)bh * NS * NS + (size_t)qt * QBLK * NS;

    __shared__ __align__(16) _Float16 Qs[QBLK * QST];   //  9728 B
    __shared__ __align__(16) _Float16 Ks[KBLK * KST];   // 19456 B
    __shared__ __align__(16) _Float16 VT[ND * VST];     // 17920 B
    __shared__ __align__(16) _Float16 Ps[QBLK * PST];   // 16896 B  (total 64000 B)

    const int srow = tid >> 4;          // 0..15
    const int sd0  = (tid & 15) * 4;    // 0..60
    const int kq   = tid >> 3;          // 0..31  (V: 4-key quad)
    const int dg   = tid & 7;           // 0..7   (V: 8-d group)

    // ---- stage Q (scaled by 1/T = 1/8, exact) ----
    #pragma unroll
    for (int it = 0; it < 4; ++it) {
        const int r = srow + 16 * it;
        float4 f = *(const float4*)&Qp[(size_t)r * ND + sd0];
        f16x4 h = { (_Float16)(f.x * 0.125f), (_Float16)(f.y * 0.125f),
                    (_Float16)(f.z * 0.125f), (_Float16)(f.w * 0.125f) };
        *(f16x4*)&Qs[r * QST + sd0] = h;
    }
    __syncthreads();

    const int q = 16 * w + lc;
    const f16x8 qf0 = lds8(&Qs[q * QST + 8 * lg]);
    const f16x8 qf1 = lds8(&Qs[q * QST + 8 * lg + 32]);

    float4 kreg[8], vreg[8];

    auto loadK = [&](int t) {
        #pragma unroll
        for (int it = 0; it < 8; ++it)
            kreg[it] = *(const float4*)&Kp[(size_t)(t * KBLK + srow + 16 * it) * ND + sd0];
    };
    auto writeK = [&]() {
        #pragma unroll
        for (int it = 0; it < 8; ++it) {
            f16x4 h = { (_Float16)kreg[it].x, (_Float16)kreg[it].y,
                        (_Float16)kreg[it].z, (_Float16)kreg[it].w };
            *(f16x4*)&Ks[(srow + 16 * it) * KST + sd0] = h;
        }
    };
    auto loadV = [&](int t) {   // thread owns keys 4kq..4kq+3 × d 8dg..8dg+7
        #pragma unroll
        for (int r = 0; r < 4; ++r)
            #pragma unroll
            for (int h = 0; h < 2; ++h)
                vreg[2 * r + h] =
                    *(const float4*)&Vp[(size_t)(t * KBLK + 4 * kq + r) * ND + 8 * dg + 4 * h];
    };
    auto writeVT = [&]() {      // in-register 4x(4|4) transpose -> b64 writes
        #pragma unroll
        for (int h = 0; h < 2; ++h)
            #pragma unroll
            for (int j = 0; j < 4; ++j) {
                f16x4 col = { (_Float16)vreg[0 + h][j], (_Float16)vreg[2 + h][j],
                              (_Float16)vreg[4 + h][j], (_Float16)vreg[6 + h][j] };
                *(f16x4*)&VT[(8 * dg + 4 * h + j) * VST + 4 * kq] = col;
            }
    };

    auto qkT = [&](f32x4 (&s)[8]) {   // S^T: rows = 128 keys (8 subtiles), cols = q
        __builtin_amdgcn_s_setprio(1);
        #pragma unroll
        for (int mt = 0; mt < 8; ++mt) {
            f16x8 a0 = lds8(&Ks[(16 * mt + lc) * KST + 8 * lg]);
            f16x8 a1 = lds8(&Ks[(16 * mt + lc) * KST + 8 * lg + 32]);
            f32x4 z = {0.f, 0.f, 0.f, 0.f};
            z = MFMA16(a0, qf0, z);
            z = MFMA16(a1, qf1, z);
            s[mt] = z;
        }
        __builtin_amdgcn_s_setprio(0);
    };

    float m = -3.0e38f, lsum = 0.0f;

    // ================= PASS A: softmax stats =================
    loadK(0);
    for (int t = 0; t < NKT; ++t) {
        __syncthreads();
        writeK();
        __syncthreads();
        loadK(t + 1 < NKT ? t + 1 : 0);

        f32x4 s[8];
        qkT(s);
        float tmax = -3.0e38f;
        #pragma unroll
        for (int mt = 0; mt < 8; ++mt)
            #pragma unroll
            for (int r = 0; r < 4; ++r)
                tmax = fmaxf(tmax, s[mt][r]);
        tmax = fmaxf(tmax, __shfl_xor(tmax, 16));
        tmax = fmaxf(tmax, __shfl_xor(tmax, 32));
        const float mn = fmaxf(m, tmax);
        float ts = 0.f;
        #pragma unroll
        for (int mt = 0; mt < 8; ++mt)
            #pragma unroll
            for (int r = 0; r < 4; ++r)
                ts += __expf(s[mt][r] - mn);
        ts += __shfl_xor(ts, 16);
        ts += __shfl_xor(ts, 32);
        lsum = lsum * __expf(m - mn) + ts;
        m = mn;
    }
    const float il = 1.0f / lsum;

    // ================= PASS B: attn write + PV =================
    f32x4 acc[4];
    #pragma unroll
    for (int dt = 0; dt < 4; ++dt) acc[dt] = {0.f, 0.f, 0.f, 0.f};

    loadK(0); loadV(0);
    for (int t = 0; t < NKT; ++t) {
        __syncthreads();
        writeK(); writeVT();
        __syncthreads();
        const int nt = t + 1 < NKT ? t + 1 : 0;
        loadK(nt); loadV(nt);

        f32x4 s[8];
        qkT(s);

        // p = exp(s-m)*il : nontemporal attn store (fp32) + P stash (f16)
        #pragma unroll
        for (int mt = 0; mt < 8; ++mt) {
            f32x4 p;
            #pragma unroll
            for (int r = 0; r < 4; ++r)
                p[r] = __expf(s[mt][r] - m) * il;
            __builtin_nontemporal_store(
                p, (f32x4*)&Ap[(size_t)q * NS + t * KBLK + 16 * mt + 4 * lg]);
            f16x4 ph = { (_Float16)p[0], (_Float16)p[1], (_Float16)p[2], (_Float16)p[3] };
            *(f16x4*)&Ps[q * PST + 16 * mt + 4 * lg] = ph;
        }
        asm volatile("s_waitcnt lgkmcnt(0)" ::: "memory");  // wave-private P rows

        // PV: O^T += V^T . P^T  (4 k-slices of 32)
        f16x8 bf[4];
        #pragma unroll
        for (int ks = 0; ks < 4; ++ks)
            bf[ks] = lds8(&Ps[q * PST + 32 * ks + 8 * lg]);
        __builtin_amdgcn_s_setprio(1);
        #pragma unroll
        for (int dt = 0; dt < 4; ++dt) {
            #pragma unroll
            for (int ks = 0; ks < 4; ++ks) {
                f16x8 af = lds8(&VT[(16 * dt + lc) * VST + 32 * ks + 8 * lg]);
                acc[dt] = MFMA16(af, bf[ks], acc[dt]);
            }
        }
        __builtin_amdgcn_s_setprio(0);
    }

    // O^T[d = 16dt+4lg+r][q] -> Op[q][d]
    #pragma unroll
    for (int dt = 0; dt < 4; ++dt)
        __builtin_nontemporal_store(
            acc[dt], (f32x4*)&Op[(size_t)q * ND + 16 * dt + 4 * lg]);
}

extern "C" void kernel_launch(void* const* d_in, const int* in_sizes, int n_in,
                              void* d_out, int out_size, void* d_ws, size_t ws_size,
                              hipStream_t stream) {
    const float* q = (const float*)d_in[0];
    const float* k = (const float*)d_in[1];
    const float* v = (const float*)d_in[2];
    float* out  = (float*)d_out;
    float* attn = out + (size_t)NB * NH * NS * ND;  // outputs: (output, attn)

    dim3 grid(NS / QBLK, NB * NH);
    sdpa_kernel<<<grid, 256, 0, stream>>>(q, k, v, out, attn);
}

// Round 6
// 116.476 us; speedup vs baseline: 1.4810x; 1.0176x over previous
//
#include <hip/hip_runtime.h>

#define NB 2
#define NH 8
#define NS 2048
#define ND 64
#define QBLK 64
#define KBLK 128
#define NKT (NS / KBLK)   // 16
#define QST 76            // Q/K LDS row stride (f16)
#define KST 76
#define VST 140           // VT row stride
#define PST 132           // P row stride

typedef _Float16 f16x4 __attribute__((ext_vector_type(4)));
typedef _Float16 f16x8 __attribute__((ext_vector_type(8)));
typedef float    f32x4 __attribute__((ext_vector_type(4)));

#define MFMA16(A,B,C) __builtin_amdgcn_mfma_f32_16x16x32_f16((A),(B),(C),0,0,0)

static __device__ __forceinline__ f16x8 cat8(f16x4 a, f16x4 b) {
    return __builtin_shufflevector(a, b, 0, 1, 2, 3, 4, 5, 6, 7);
}
static __device__ __forceinline__ f16x8 lds8(const _Float16* p) {
    f16x4 a = *(const f16x4*)p;          // 8B-aligned ds_read_b64 pair
    f16x4 b = *(const f16x4*)(p + 4);
    return cat8(a, b);
}
// write-visibility barrier: my LDS writes drained, then rendezvous
static __device__ __forceinline__ void bar_w() {
    asm volatile("s_waitcnt lgkmcnt(0)" ::: "memory");
    __builtin_amdgcn_sched_barrier(0);
    __builtin_amdgcn_s_barrier();
    __builtin_amdgcn_sched_barrier(0);
    asm volatile("" ::: "memory");
}

__global__ __launch_bounds__(256, 3)
void sdpa_kernel(const float* __restrict__ Qg, const float* __restrict__ Kg,
                 const float* __restrict__ Vg, float* __restrict__ Og,
                 float* __restrict__ Ag)
{
    const int tid  = threadIdx.x;
    const int w    = tid >> 6;
    const int lane = tid & 63;
    const int lg   = lane >> 4;
    const int lc   = lane & 15;
    const int qt   = blockIdx.x;
    const int bh   = blockIdx.y;

    const size_t base = (size_t)bh * NS * ND;
    const float* Qp = Qg + base + (size_t)qt * QBLK * ND;
    const float* Kp = Kg + base;
    const float* Vp = Vg + base;
    float*       Op = Og + base + (size_t)qt * QBLK * ND;
    float*       Ap = Ag + (size_t)bh * NS * NS + (size_t)qt * QBLK * NS;

    // pool: Ks 19456 | VT 17920 | union(Qs 9728, Ps 16896) = 54272 B -> 3 blocks/CU
    __shared__ __align__(16) unsigned char pool[54272];
    _Float16* Ks = (_Float16*)pool;
    _Float16* VT = (_Float16*)(pool + 19456);
    _Float16* Qs = (_Float16*)(pool + 37376);   // dead after qf loads
    _Float16* Ps = (_Float16*)(pool + 37376);   // overlays Qs in pass B

    const int srow = tid >> 4;          // 0..15
    const int sd0  = (tid & 15) * 4;    // 0..60
    const int kq   = tid >> 3;          // 0..31  (V: 4-key quad)
    const int dg   = tid & 7;           // 0..7   (V: 8-d group)

    // ---- stage Q (scaled by 1/T = 1/8, exact) ----
    #pragma unroll
    for (int it = 0; it < 4; ++it) {
        const int r = srow + 16 * it;
        float4 f = *(const float4*)&Qp[(size_t)r * ND + sd0];
        f16x4 h = { (_Float16)(f.x * 0.125f), (_Float16)(f.y * 0.125f),
                    (_Float16)(f.z * 0.125f), (_Float16)(f.w * 0.125f) };
        *(f16x4*)&Qs[r * QST + sd0] = h;
    }
    __syncthreads();

    const int q = 16 * w + lc;
    const f16x8 qf0 = lds8(&Qs[q * QST + 8 * lg]);
    const f16x8 qf1 = lds8(&Qs[q * QST + 8 * lg + 32]);

    float4 kreg[8];
    auto loadK = [&](int t) {
        #pragma unroll
        for (int it = 0; it < 8; ++it)
            kreg[it] = *(const float4*)&Kp[(size_t)(t * KBLK + srow + 16 * it) * ND + sd0];
    };
    auto writeK = [&]() {
        #pragma unroll
        for (int it = 0; it < 8; ++it) {
            f16x4 h = { (_Float16)kreg[it].x, (_Float16)kreg[it].y,
                        (_Float16)kreg[it].z, (_Float16)kreg[it].w };
            *(f16x4*)&Ks[(srow + 16 * it) * KST + sd0] = h;
        }
    };

    float m = -3.0e38f, lsum = 0.0f;

    // ================= PASS A: softmax stats (m, l) =================
    loadK(0);
    for (int t = 0; t < NKT; ++t) {
        writeK();
        loadK(t + 1 < NKT ? t + 1 : 0);
        bar_w();                       // all waves' K writes visible

        f32x4 s[8];
        __builtin_amdgcn_s_setprio(1);
        #pragma unroll
        for (int mt = 0; mt < 8; ++mt) {
            f16x8 a0 = lds8(&Ks[(16 * mt + lc) * KST + 8 * lg]);
            f16x8 a1 = lds8(&Ks[(16 * mt + lc) * KST + 8 * lg + 32]);
            f32x4 z = {0.f, 0.f, 0.f, 0.f};
            z = MFMA16(a0, qf0, z);
            z = MFMA16(a1, qf1, z);
            s[mt] = z;
        }
        __builtin_amdgcn_s_setprio(0);

        float tmax = -3.0e38f;
        #pragma unroll
        for (int mt = 0; mt < 8; ++mt)
            #pragma unroll
            for (int r = 0; r < 4; ++r)
                tmax = fmaxf(tmax, s[mt][r]);
        tmax = fmaxf(tmax, __shfl_xor(tmax, 16));
        tmax = fmaxf(tmax, __shfl_xor(tmax, 32));
        const float mn = fmaxf(m, tmax);
        float ts = 0.f;
        #pragma unroll
        for (int mt = 0; mt < 8; ++mt)
            #pragma unroll
            for (int r = 0; r < 4; ++r)
                ts += __expf(s[mt][r] - mn);
        ts += __shfl_xor(ts, 16);
        ts += __shfl_xor(ts, 32);
        lsum = lsum * __expf(m - mn) + ts;
        m = mn;

        bar_w();                       // all waves done reading Ks
    }
    const float il = 1.0f / lsum;

    // ================= PASS B: attn write + PV =================
    f32x4 acc[4];
    #pragma unroll
    for (int dt = 0; dt < 4; ++dt) acc[dt] = {0.f, 0.f, 0.f, 0.f};

    {
        float4 vreg[8];
        auto loadV = [&](int t) {   // thread owns keys 4kq..4kq+3 x d 8dg..8dg+7
            #pragma unroll
            for (int r = 0; r < 4; ++r)
                #pragma unroll
                for (int h = 0; h < 2; ++h)
                    vreg[2 * r + h] = *(const float4*)
                        &Vp[(size_t)(t * KBLK + 4 * kq + r) * ND + 8 * dg + 4 * h];
        };
        auto writeVT = [&]() {      // in-register 4x4 transpose -> b64 writes
            #pragma unroll
            for (int h = 0; h < 2; ++h)
                #pragma unroll
                for (int j = 0; j < 4; ++j) {
                    f16x4 col = { (_Float16)vreg[0 + h][j], (_Float16)vreg[2 + h][j],
                                  (_Float16)vreg[4 + h][j], (_Float16)vreg[6 + h][j] };
                    *(f16x4*)&VT[(8 * dg + 4 * h + j) * VST + 4 * kq] = col;
                }
        };

        loadK(0); loadV(0);
        for (int t = 0; t < NKT; ++t) {
            writeK(); writeVT();
            const int nt = t + 1 < NKT ? t + 1 : 0;
            loadK(nt); loadV(nt);
            bar_w();                   // all waves' K/VT writes visible

            // per-mt fused: QK^T -> p -> attn store + P stash (low VGPR pressure)
            #pragma unroll
            for (int mt = 0; mt < 8; ++mt) {
                f16x8 a0 = lds8(&Ks[(16 * mt + lc) * KST + 8 * lg]);
                f16x8 a1 = lds8(&Ks[(16 * mt + lc) * KST + 8 * lg + 32]);
                f32x4 z = {0.f, 0.f, 0.f, 0.f};
                __builtin_amdgcn_s_setprio(1);
                z = MFMA16(a0, qf0, z);
                z = MFMA16(a1, qf1, z);
                __builtin_amdgcn_s_setprio(0);
                f32x4 p;
                #pragma unroll
                for (int r = 0; r < 4; ++r)
                    p[r] = __expf(z[r] - m) * il;
                __builtin_nontemporal_store(
                    p, (f32x4*)&Ap[(size_t)q * NS + t * KBLK + 16 * mt + 4 * lg]);
                f16x4 ph = { (_Float16)p[0], (_Float16)p[1],
                             (_Float16)p[2], (_Float16)p[3] };
                *(f16x4*)&Ps[q * PST + 16 * mt + 4 * lg] = ph;
            }
            asm volatile("s_waitcnt lgkmcnt(0)" ::: "memory");  // wave-private P rows
            __builtin_amdgcn_sched_barrier(0);

            // PV: O^T += V^T . P^T  (4 k-slices of 32)
            f16x8 bf[4];
            #pragma unroll
            for (int ks = 0; ks < 4; ++ks)
                bf[ks] = lds8(&Ps[q * PST + 32 * ks + 8 * lg]);
            __builtin_amdgcn_s_setprio(1);
            #pragma unroll
            for (int dt = 0; dt < 4; ++dt) {
                #pragma unroll
                for (int ks = 0; ks < 4; ++ks) {
                    f16x8 af = lds8(&VT[(16 * dt + lc) * VST + 32 * ks + 8 * lg]);
                    acc[dt] = MFMA16(af, bf[ks], acc[dt]);
                }
            }
            __builtin_amdgcn_s_setprio(0);

            bar_w();                   // all waves done reading Ks/VT/Ps
        }
    }

    // O^T[d = 16dt+4lg+r][q] -> Op[q][d]
    #pragma unroll
    for (int dt = 0; dt < 4; ++dt)
        __builtin_nontemporal_store(
            acc[dt], (f32x4*)&Op[(size_t)q * ND + 16 * dt + 4 * lg]);
}

extern "C" void kernel_launch(void* const* d_in, const int* in_sizes, int n_in,
                              void* d_out, int out_size, void* d_ws, size_t ws_size,
                              hipStream_t stream) {
    const float* q = (const float*)d_in[0];
    const float* k = (const float*)d_in[1];
    const float* v = (const float*)d_in[2];
    float* out  = (float*)d_out;
    float* attn = out + (size_t)NB * NH * NS * ND;  // outputs: (output, attn)

    dim3 grid(NS / QBLK, NB * NH);
    sdpa_kernel<<<grid, 256, 0, stream>>>(q, k, v, out, attn);
}